// Round 14
// baseline (1065.953 us; speedup 1.0000x reference)
//
#include <hip/hip_runtime.h>
#include <stdint.h>

// ---------------------------------------------------------------------------
// Types / helpers
// ---------------------------------------------------------------------------
typedef float  f32x4  __attribute__((ext_vector_type(4)));
typedef __bf16 bf16x8 __attribute__((ext_vector_type(8)));

#define DEV __device__ __forceinline__

DEV short f2b(float f) {  // fp32 -> bf16 bits, round-to-nearest-even
    union { float f; unsigned u; } c; c.f = f;
    unsigned u = c.u;
    unsigned r = (u + 0x7fffu + ((u >> 16) & 1u)) >> 16;
    return (short)r;
}

DEV void gload_lds16(const void* g, void* l) {
    // async global->LDS, 16B per lane; LDS dest = wave-uniform base + lane*16
    __builtin_amdgcn_global_load_lds(
        (const __attribute__((address_space(1))) void*)g,
        (__attribute__((address_space(3))) void*)l, 16, 0, 0);
}

// ---------------------------------------------------------------------------
// GEMM body: C = A(bf16,[M,K]) * B^T(bf16,[N,K]). 64x96 tiles, 40 KB LDS,
// 4 blocks/CU, 2-phase prefetch, one vmcnt(0)+s_barrier per k-tile,
// XOR-swizzle via pre-swizzled global source.
// CM (r14): XCD-chunk orientation. CM=1 -> column-major chunks (same-XCD
// blocks share B col-tiles; working set = few B-tiles + all A-bands ~3.4MB
// < 4MB per-XCD L2). CM=0 -> row-major (for FFN2 whose A-bands are 4x big).
// MODE 1: +bias(bq/bk/bv select), scatter q(*0.125)/k, v transposed
// MODE 2: +bias, exact GELU, bf16 row-major                    [FFN1]
// MODE 3: fp32 partial store per split (no bias)               [FFN2 split-K]
// ---------------------------------------------------------------------------
template<int MODE, int NSPLIT, int CM>
DEV void gemm_body(
    const short* __restrict__ A, const short* __restrict__ Bt,
    const float* __restrict__ bias, const float* __restrict__ biask,
    const float* __restrict__ biasv,
    float* __restrict__ outf, short* __restrict__ o0,
    short* __restrict__ o1, short* __restrict__ o2,
    int M, int N, int K)
{
    constexpr int BM = 64, BN = 96, BK = 64;
    constexpr int FM = 2, FN = 3;
    __shared__ __align__(16) short As[2][BM * BK];   // 16 KB
    __shared__ __align__(16) short Bs[2][BN * BK];   // 24 KB

    const int tid  = threadIdx.x;
    const int w    = tid >> 6, lane = tid & 63;
    const int wr   = w >> 1,  wc   = w & 1;
    const int l16  = lane & 15, lhi = lane >> 4, sw = lane & 7;

    // bijective XCD-aware remap (nwg % 8 == 0 for all grids)
    const int gx   = gridDim.x, gy = gridDim.y;
    const int nwg  = gx * gy;
    const int flat = blockIdx.y * gx + blockIdx.x;
    const int nf   = (flat & 7) * (nwg >> 3) + (flat >> 3);
    int bx, by;
    if constexpr (CM) { bx = nf / gy; by = nf - bx * gy; }   // column-major chunks
    else              { bx = nf % gx; by = nf / gx; }        // row-major chunks

    const int kz = (NSPLIT > 1) ? blockIdx.z : 0;

    const short* Ab = A  + (long)by * BM * K;
    const short* Bb = Bt + (long)bx * BN * K;

    const int ktPer = (K >> 6) / NSPLIT;
    const int ktBeg = kz * ktPer, ktEnd = ktBeg + ktPer;

    f32x4 acc[FM][FN];
#pragma unroll
    for (int m = 0; m < FM; ++m)
#pragma unroll
        for (int n = 0; n < FN; ++n) acc[m][n] = (f32x4)(0.0f);

    auto stage = [&](int buf, int kt) {
        const short* Ag = Ab + kt * BK;
#pragma unroll
        for (int i = 0; i < BM / 32; ++i) {          // 2 calls: 512 segs
            int seg = i * 256 + tid;
            int row = seg >> 3;                      // 0..63
            int gcs = (seg & 7) ^ (row & 7);         // pre-swizzled source
            gload_lds16(Ag + (long)row * K + gcs * 8, &As[buf][(i * 256 + w * 64) * 8]);
        }
        const short* Bg = Bb + kt * BK;
#pragma unroll
        for (int i = 0; i < BN / 32; ++i) {          // 3 calls: 768 segs
            int seg = i * 256 + tid;
            int row = seg >> 3;                      // 0..95
            int gcs = (seg & 7) ^ (row & 7);
            gload_lds16(Bg + (long)row * K + gcs * 8, &Bs[buf][(i * 256 + w * 64) * 8]);
        }
    };

    stage(0, ktBeg);
    asm volatile("s_waitcnt vmcnt(0)" ::: "memory");
    __builtin_amdgcn_s_barrier();

    int cur = 0;
    for (int kt = ktBeg; kt < ktEnd; ++kt) {
        if (kt + 1 < ktEnd) stage(cur ^ 1, kt + 1);     // prefetch next tile
        const short* Ac = &As[cur][0];
        const short* Bc = &Bs[cur][0];
#pragma unroll
        for (int kk = 0; kk < 2; ++kk) {
            bf16x8 af[FM], bfr[FN];
#pragma unroll
            for (int m = 0; m < FM; ++m) {
                int ar = wr * 32 + m * 16 + l16;
                int ks = (kk * 4 + lhi) ^ sw;           // ar&7 == sw
                af[m] = *(const bf16x8*)(Ac + ar * BK + ks * 8);
            }
#pragma unroll
            for (int n = 0; n < FN; ++n) {
                int br = wc * 48 + n * 16 + l16;
                int ks = (kk * 4 + lhi) ^ sw;           // br&7 == sw
                bfr[n] = *(const bf16x8*)(Bc + br * BK + ks * 8);
            }
#pragma unroll
            for (int m = 0; m < FM; ++m)
#pragma unroll
                for (int n = 0; n < FN; ++n)
                    acc[m][n] = __builtin_amdgcn_mfma_f32_16x16x32_bf16(
                        af[m], bfr[n], acc[m][n], 0, 0, 0);
        }
        asm volatile("s_waitcnt vmcnt(0)" ::: "memory");
        __builtin_amdgcn_s_barrier();
        cur ^= 1;
    }

    // Epilogue. C/D frag mapping: col = lane&15, row = (lane>>4)*4 + reg.
    const int m0 = by * BM, n0 = bx * BN;
#pragma unroll
    for (int m = 0; m < FM; ++m) {
#pragma unroll
        for (int n = 0; n < FN; ++n) {
            const int grow0 = m0 + wr * 32 + m * 16 + lhi * 4;
            const int gcol  = n0 + wc * 48 + n * 16 + l16;
#pragma unroll
            for (int r = 0; r < 4; ++r) {
                float val = acc[m][n][r];
                int grow = grow0 + r;
                if constexpr (MODE == 1) {
                    int d  = gcol & 63;
                    int hh = gcol >> 6;                 // 0..35
                    float bval = (hh < 12) ? bias[gcol]
                               : (hh < 24) ? biask[gcol - 768]
                                           : biasv[gcol - 1536];
                    float v = val + bval;
                    int bb = grow >> 9, s = grow & 511;
                    if (hh < 12) {
                        o0[((long)((bb * 12 + hh) * 512 + s) << 6) + d] = f2b(v * 0.125f);
                    } else if (hh < 24) {
                        o1[((long)((bb * 12 + (hh - 12)) * 512 + s) << 6) + d] = f2b(v);
                    } else {                             // V stored transposed [B,H,64,512]
                        o2[((long)((bb * 12 + (hh - 24)) * 64 + d) << 9) + s] = f2b(v);
                    }
                } else if constexpr (MODE == 2) {
                    float v = val + bias[gcol];
                    v = 0.5f * v * (1.0f + erff(v * 0.70710678118f));
                    o0[(long)grow * N + gcol] = f2b(v);
                } else {                                 // MODE 3: fp32 partial store
                    outf[(long)kz * M * N + (long)grow * N + gcol] = val;
                }
            }
        }
    }
}

__global__ __launch_bounds__(256) void k_qkv(
    const short* A, const short* Bt,
    const float* bq, const float* bk, const float* bv,
    short* q, short* k, short* vt)
{ gemm_body<1, 1, 1>(A, Bt, bq, bk, bv, nullptr, q, k, vt, 2048, 2304, 768); }

__global__ __launch_bounds__(256) void k_ffn1(
    const short* A, const short* Bt, const float* bias, short* h)
{ gemm_body<2, 1, 1>(A, Bt, bias, nullptr, nullptr, nullptr, h, nullptr, nullptr, 2048, 3072, 768); }

__global__ __launch_bounds__(256) void k_ffn2(
    const short* A, const short* Bt, float* part)
{ gemm_body<3, 4, 0>(A, Bt, nullptr, nullptr, nullptr, part, nullptr, nullptr, nullptr, 2048, 768, 3072); }

// ---------------------------------------------------------------------------
// Fused flash attention (r13-verified). One block per (64-row q-tile, head).
// Swapped QK^T; fixed-shift softmax p = exp(s - 8) (scores bounded << 88);
// packed short4 P-writes; K/V KVBLK=64 dbuf 2-phase.
// x += O (rows/cols exclusive -> plain +=).
// ---------------------------------------------------------------------------
__global__ __launch_bounds__(256) void k_attn(
    const short* __restrict__ Qg,   // [48][512][64] bf16, pre-scaled by 1/8
    const short* __restrict__ Kg,   // [48][512][64]
    const short* __restrict__ VTg,  // [48][64][512]  (V^T per head)
    float* __restrict__ x)          // [2048][768] +=
{
    __shared__ __align__(16) short Qs[64 * 64];        // 8 KB
    __shared__ __align__(16) short Ks[2][64 * 64];     // 16 KB
    __shared__ __align__(16) short Vs[2][64 * 64];     // 16 KB
    __shared__ __align__(16) short Ps[4][16 * 64];     // 8 KB (per-wave P tile)

    const int tid = threadIdx.x;
    const int w = tid >> 6, lane = tid & 63;
    const int l16 = lane & 15, lhi = lane >> 4;

    // XCD grouping: 48 consecutive nf (6 heads) per XCD
    const int f  = blockIdx.y * 8 + blockIdx.x;        // z*8 + qt
    const int nf = (f & 7) * 48 + (f >> 3);
    const int z  = nf >> 3, qt = nf & 7;
    const int q0 = qt * 64;

    const short* Qb = Qg  + (long)z * 512 * 64 + q0 * 64;   // contiguous 64x64
    const short* Kb = Kg  + (long)z * 512 * 64;
    const short* Vb = VTg + (long)z * 64 * 512;

    auto stageQ = [&]() {
#pragma unroll
        for (int i = 0; i < 2; ++i) {
            int seg = i * 256 + tid;
            int row = seg >> 3;
            int gc  = (seg & 7) ^ (row & 7);
            gload_lds16(Qb + row * 64 + gc * 8, Qs + (i * 256 + w * 64) * 8);
        }
    };
    auto stageK = [&](int buf, int kt) {
#pragma unroll
        for (int i = 0; i < 2; ++i) {
            int seg = i * 256 + tid;
            int row = seg >> 3;
            int gc  = (seg & 7) ^ (row & 7);
            gload_lds16(Kb + (kt * 64 + row) * 64 + gc * 8, &Ks[buf][(i * 256 + w * 64) * 8]);
        }
    };
    auto stageV = [&](int buf, int kt) {
#pragma unroll
        for (int i = 0; i < 2; ++i) {
            int seg = i * 256 + tid;
            int row = seg >> 3;                         // d index
            int gc  = (seg & 7) ^ (row & 7);
            gload_lds16(Vb + (long)row * 512 + kt * 64 + gc * 8, &Vs[buf][(i * 256 + w * 64) * 8]);
        }
    };

    stageQ(); stageK(0, 0); stageV(0, 0);
    asm volatile("s_waitcnt vmcnt(0)" ::: "memory");
    __syncthreads();

    // Q b-frags for wave's 16 q-rows (row = w*16 + l16), loaded once
    bf16x8 bq[2];
    {
        int qr = w * 16 + l16;
#pragma unroll
        for (int kk = 0; kk < 2; ++kk)
            bq[kk] = *(const bf16x8*)(Qs + qr * 64 + (((kk * 4 + lhi) ^ (l16 & 7)) * 8));
    }

    float l = 0.0f;
    f32x4 acc[4];
#pragma unroll
    for (int bn = 0; bn < 4; ++bn) acc[bn] = (f32x4)(0.0f);

    int cur = 0;
    for (int kt = 0; kt < 8; ++kt) {
        if (kt < 7) { stageK(cur ^ 1, kt + 1); stageV(cur ^ 1, kt + 1); }

        // S^T = K_tile(64 kpos x 64 d) · Q^T : lane holds S[q=l16][k=km*16+lhi*4+r]
        f32x4 s[4];
#pragma unroll
        for (int km = 0; km < 4; ++km) s[km] = (f32x4)(0.0f);
#pragma unroll
        for (int kk = 0; kk < 2; ++kk) {
#pragma unroll
            for (int km = 0; km < 4; ++km) {
                int kr = km * 16 + l16;
                bf16x8 ak = *(const bf16x8*)(&Ks[cur][kr * 64 + (((kk * 4 + lhi) ^ (l16 & 7)) * 8)]);
                s[km] = __builtin_amdgcn_mfma_f32_16x16x32_bf16(ak, bq[kk], s[km], 0, 0, 0);
            }
        }

        // fixed-shift softmax accumulation for q = l16 (no max tracking)
        float p[16];
        float ts = 0.0f;
#pragma unroll
        for (int km = 0; km < 4; ++km)
#pragma unroll
            for (int r = 0; r < 4; ++r) {
                float e = __expf(s[km][r] - 8.0f);
                p[km * 4 + r] = e; ts += e;
            }
        ts += __shfl_xor(ts, 16);
        ts += __shfl_xor(ts, 32);
        l += ts;

        // packed P write (bf16) to per-wave LDS tile in A-frag layout.
        // k = km*16 + lhi*4 + r -> granule g = 2km + (lhi>>1), elem e = (lhi&1)*4 + r
        {
            short* Pw = &Ps[w][0];
#pragma unroll
            for (int km = 0; km < 4; ++km) {
                int g = km * 2 + (lhi >> 1);
                short4 pk;
                pk.x = f2b(p[km * 4 + 0]);
                pk.y = f2b(p[km * 4 + 1]);
                pk.z = f2b(p[km * 4 + 2]);
                pk.w = f2b(p[km * 4 + 3]);
                *(short4*)(Pw + l16 * 64 + ((g ^ (l16 & 7)) * 8) + (lhi & 1) * 4) = pk;
            }
        }

        // PV: O(16q x 64d) += P(16q x 64k) · V(64k x 64d)
#pragma unroll
        for (int kk = 0; kk < 2; ++kk) {
            bf16x8 ap = *(const bf16x8*)(&Ps[w][l16 * 64 + (((kk * 4 + lhi) ^ (l16 & 7)) * 8)]);
#pragma unroll
            for (int bn = 0; bn < 4; ++bn) {
                int vr = bn * 16 + l16;
                bf16x8 bv = *(const bf16x8*)(&Vs[cur][vr * 64 + (((kk * 4 + lhi) ^ (l16 & 7)) * 8)]);
                acc[bn] = __builtin_amdgcn_mfma_f32_16x16x32_bf16(ap, bv, acc[bn], 0, 0, 0);
            }
        }

        asm volatile("s_waitcnt vmcnt(0)" ::: "memory");
        __builtin_amdgcn_s_barrier();
        cur ^= 1;
    }

    // epilogue: normalize and accumulate into x
    float inv = 1.0f / l;
    float invr[4];
#pragma unroll
    for (int r = 0; r < 4; ++r) invr[r] = __shfl(inv, lhi * 4 + r);
    const int zb = z / 12, zh = z - (z / 12) * 12;
#pragma unroll
    for (int bn = 0; bn < 4; ++bn)
#pragma unroll
        for (int r = 0; r < 4; ++r) {
            long idx = ((long)(zb * 512 + q0 + w * 16 + lhi * 4 + r)) * 768 + zh * 64 + bn * 16 + l16;
            x[idx] += acc[bn][r] * invr[r];
        }
}

// ---------------------------------------------------------------------------
// LayerNorm: one wave per row (768 fp32), write bf16
// ---------------------------------------------------------------------------
__global__ __launch_bounds__(256) void k_ln(
    const float* __restrict__ x, const float* __restrict__ g,
    const float* __restrict__ be, short* __restrict__ out)
{
    int row  = blockIdx.x * 4 + (threadIdx.x >> 6);
    int lane = threadIdx.x & 63;
    const float4* xr = (const float4*)(x + (long)row * 768);
    float4 v0 = xr[lane], v1 = xr[lane + 64], v2 = xr[lane + 128];
    float f[12] = {v0.x, v0.y, v0.z, v0.w, v1.x, v1.y, v1.z, v1.w, v2.x, v2.y, v2.z, v2.w};

    float s = 0.f;
#pragma unroll
    for (int j = 0; j < 12; ++j) s += f[j];
#pragma unroll
    for (int o = 32; o; o >>= 1) s += __shfl_xor(s, o);
    float mu = s * (1.0f / 768.0f);
    float s2 = 0.f;
#pragma unroll
    for (int j = 0; j < 12; ++j) { f[j] -= mu; s2 += f[j] * f[j]; }
#pragma unroll
    for (int o = 32; o; o >>= 1) s2 += __shfl_xor(s2, o);
    float rstd = rsqrtf(s2 * (1.0f / 768.0f) + 1e-5f);

    const float4* gr = (const float4*)g;
    const float4* br = (const float4*)be;
    short4* orow = (short4*)(out + (long)row * 768);
#pragma unroll
    for (int jb = 0; jb < 3; ++jb) {
        float4 gg = gr[lane + 64 * jb], bb = br[lane + 64 * jb];
        short4 o4;
        o4.x = f2b(f[4 * jb + 0] * rstd * gg.x + bb.x);
        o4.y = f2b(f[4 * jb + 1] * rstd * gg.y + bb.y);
        o4.z = f2b(f[4 * jb + 2] * rstd * gg.z + bb.z);
        o4.w = f2b(f[4 * jb + 3] * rstd * gg.w + bb.w);
        orow[lane + 64 * jb] = o4;
    }
}

// ---------------------------------------------------------------------------
// FFN2 split-K reduce (4 partials) fused with next block's LN1:
//   x += p0+p1+p2+p3 + b1 ; if DO_LN: lnb = LN(x)*g + be  (one wave per row)
// ---------------------------------------------------------------------------
template<int DO_LN>
__global__ __launch_bounds__(256) void k_redln(
    const float* __restrict__ part, const float* __restrict__ bias,
    float* __restrict__ x, const float* __restrict__ g,
    const float* __restrict__ be, short* __restrict__ out)
{
    int row  = blockIdx.x * 4 + (threadIdx.x >> 6);
    int lane = threadIdx.x & 63;
    const long plane = 2048l * 768 / 4;                // float4 units per plane
    const float4* p0 = (const float4*)part + (long)row * 192;
    const float4* p1 = p0 + plane;
    const float4* p2 = p1 + plane;
    const float4* p3 = p2 + plane;
    const float4* b4 = (const float4*)bias;
    float4* xr = (float4*)(x + (long)row * 768);

    float f[12];
#pragma unroll
    for (int jb = 0; jb < 3; ++jb) {
        int idx = lane + 64 * jb;
        float4 a = p0[idx], b = p1[idx], c2 = p2[idx], d = p3[idx];
        float4 c = b4[idx], xv = xr[idx];
        xv.x += a.x + b.x + c2.x + d.x + c.x;
        xv.y += a.y + b.y + c2.y + d.y + c.y;
        xv.z += a.z + b.z + c2.z + d.z + c.z;
        xv.w += a.w + b.w + c2.w + d.w + c.w;
        xr[idx] = xv;
        f[4 * jb + 0] = xv.x; f[4 * jb + 1] = xv.y;
        f[4 * jb + 2] = xv.z; f[4 * jb + 3] = xv.w;
    }

    if constexpr (DO_LN) {
        float s = 0.f;
#pragma unroll
        for (int j = 0; j < 12; ++j) s += f[j];
#pragma unroll
        for (int o = 32; o; o >>= 1) s += __shfl_xor(s, o);
        float mu = s * (1.0f / 768.0f);
        float s2 = 0.f;
#pragma unroll
        for (int j = 0; j < 12; ++j) { f[j] -= mu; s2 += f[j] * f[j]; }
#pragma unroll
        for (int o = 32; o; o >>= 1) s2 += __shfl_xor(s2, o);
        float rstd = rsqrtf(s2 * (1.0f / 768.0f) + 1e-5f);

        const float4* gr = (const float4*)g;
        const float4* br = (const float4*)be;
        short4* orow = (short4*)(out + (long)row * 768);
#pragma unroll
        for (int jb = 0; jb < 3; ++jb) {
            float4 gg = gr[lane + 64 * jb], bb = br[lane + 64 * jb];
            short4 o4;
            o4.x = f2b(f[4 * jb + 0] * rstd * gg.x + bb.x);
            o4.y = f2b(f[4 * jb + 1] * rstd * gg.y + bb.y);
            o4.z = f2b(f[4 * jb + 2] * rstd * gg.z + bb.z);
            o4.w = f2b(f[4 * jb + 3] * rstd * gg.w + bb.w);
            orow[lane + 64 * jb] = o4;
        }
    }
}

// ---------------------------------------------------------------------------
// Weight prep kernels
// ---------------------------------------------------------------------------
__global__ __launch_bounds__(256) void transpose_w(
    const float* __restrict__ in, short* __restrict__ out, int R, int C)
{
    __shared__ float t[32][33];
    int r0 = blockIdx.y * 32, c0 = blockIdx.x * 32;
    int tx = threadIdx.x & 31, ty = threadIdx.x >> 5;
#pragma unroll
    for (int p = 0; p < 4; ++p)
        t[ty + 8 * p][tx] = in[(long)(r0 + ty + 8 * p) * C + c0 + tx];
    __syncthreads();
#pragma unroll
    for (int p = 0; p < 4; ++p)
        out[(long)(c0 + ty + 8 * p) * R + r0 + tx] = f2b(t[tx][ty + 8 * p]);
}

// merged 3-way 768x768 transpose (Wq/Wk/Wv)
__global__ __launch_bounds__(256) void transpose_w3(
    const float* __restrict__ Wq, const float* __restrict__ Wk,
    const float* __restrict__ Wv, short* __restrict__ out)
{
    const float* in = (blockIdx.z == 0) ? Wq : (blockIdx.z == 1) ? Wk : Wv;
    short* o = out + (long)blockIdx.z * 768 * 768;
    __shared__ float t[32][33];
    int r0 = blockIdx.y * 32, c0 = blockIdx.x * 32;
    int tx = threadIdx.x & 31, ty = threadIdx.x >> 5;
#pragma unroll
    for (int p = 0; p < 4; ++p)
        t[ty + 8 * p][tx] = in[(long)(r0 + ty + 8 * p) * 768 + c0 + tx];
    __syncthreads();
#pragma unroll
    for (int p = 0; p < 4; ++p)
        o[(long)(c0 + ty + 8 * p) * 768 + r0 + tx] = f2b(t[tx][ty + 8 * p]);
}

// ---------------------------------------------------------------------------
// Host launcher
// ---------------------------------------------------------------------------
extern "C" void kernel_launch(void* const* d_in, const int* in_sizes, int n_in,
                              void* d_out, int out_size, void* d_ws, size_t ws_size,
                              hipStream_t stream)
{
    (void)in_sizes; (void)n_in; (void)out_size; (void)ws_size;
    const float* x_in = (const float*)d_in[0];
    const float* Wq  = (const float*)d_in[1];
    const float* bq  = (const float*)d_in[2];
    const float* Wk  = (const float*)d_in[3];
    const float* bk  = (const float*)d_in[4];
    const float* Wv  = (const float*)d_in[5];
    const float* bv  = (const float*)d_in[6];
    const float* g1  = (const float*)d_in[7];
    const float* be1 = (const float*)d_in[8];
    const float* g2  = (const float*)d_in[9];
    const float* be2 = (const float*)d_in[10];
    const float* W0  = (const float*)d_in[11];
    const float* b0  = (const float*)d_in[12];
    const float* W1  = (const float*)d_in[13];
    const float* b1  = (const float*)d_in[14];

    float* x = (float*)d_out;   // residual stream lives in d_out, fp32 [2048,768]

    char* ws = (char*)d_ws;
    size_t off = 0;
    auto alloc = [&](size_t bytes) -> char* {
        char* p = ws + off; off = (off + bytes + 255) & ~(size_t)255; return p;
    };
    short* wqkvt = (short*)alloc(2304l * 768 * 2);   // [Wq^T;Wk^T;Wv^T]
    short* w0t   = (short*)alloc(3072l * 768 * 2);
    short* w1t   = (short*)alloc(768l * 3072 * 2);
    short* lnb   = (short*)alloc(2048l * 768 * 2);   // LN output
    short* q     = (short*)alloc(2048l * 768 * 2);   // [B,H,512,64], pre-scaled 1/8
    short* k     = (short*)alloc(2048l * 768 * 2);   // [B,H,512,64]
    short* vt    = (short*)alloc(2048l * 768 * 2);   // [B,H,64,512]  (V^T)
    short* h     = (short*)alloc(2048l * 3072 * 2);  // FFN hidden
    float* part  = (float*)alloc(4l * 2048 * 768 * 4); // FFN2 split-K=4 partials

    hipMemcpyAsync(x, x_in, 2048l * 768 * 4, hipMemcpyDeviceToDevice, stream);

    transpose_w3<<<dim3(24, 24, 3), 256, 0, stream>>>(Wq, Wk, Wv, wqkvt);
    transpose_w<<<dim3(96, 24), 256, 0, stream>>>(W0, w0t, 768, 3072);
    transpose_w<<<dim3(24, 96), 256, 0, stream>>>(W1, w1t, 3072, 768);

    for (int it = 0; it < 12; ++it) {
        if (it == 0)
            k_ln<<<512, 256, 0, stream>>>(x, g1, be1, lnb);
        // QKV: 64x96 tiles, 768 blocks, column-major XCD chunks
        k_qkv<<<dim3(24, 32), 256, 0, stream>>>(lnb, wqkvt, bq, bk, bv, q, k, vt);
        // fused flash attention: x += softmax(q k^T) v
        k_attn<<<dim3(8, 48), 256, 0, stream>>>(q, k, vt, x);
        // LN2
        k_ln<<<512, 256, 0, stream>>>(x, g2, be2, lnb);
        // h = gelu(ln2 @ W0 + b0): 1024 blocks, column-major XCD chunks
        k_ffn1<<<dim3(32, 32), 256, 0, stream>>>(lnb, w0t, b0, h);
        // FFN2: split-K=4 fp32 partials, 1024 blocks, row-major chunks
        k_ffn2<<<dim3(8, 32, 4), 256, 0, stream>>>(h, w1t, part);
        // x += p0+p1+p2+p3 + b1, fused with LN1 of the next block
        if (it < 11)
            k_redln<1><<<512, 256, 0, stream>>>(part, b1, x, g1, be1, lnb);
        else
            k_redln<0><<<512, 256, 0, stream>>>(part, b1, x, nullptr, nullptr, nullptr);
    }
}

// Round 15
// 1008.097 us; speedup vs baseline: 1.0574x; 1.0574x over previous
//
#include <hip/hip_runtime.h>
#include <stdint.h>

// ---------------------------------------------------------------------------
// Types / helpers
// ---------------------------------------------------------------------------
typedef float  f32x4  __attribute__((ext_vector_type(4)));
typedef __bf16 bf16x8 __attribute__((ext_vector_type(8)));

#define DEV __device__ __forceinline__

DEV short f2b(float f) {  // fp32 -> bf16 bits, round-to-nearest-even
    union { float f; unsigned u; } c; c.f = f;
    unsigned u = c.u;
    unsigned r = (u + 0x7fffu + ((u >> 16) & 1u)) >> 16;
    return (short)r;
}

DEV void gload_lds16(const void* g, void* l) {
    // async global->LDS, 16B per lane; LDS dest = wave-uniform base + lane*16
    __builtin_amdgcn_global_load_lds(
        (const __attribute__((address_space(1))) void*)g,
        (__attribute__((address_space(3))) void*)l, 16, 0, 0);
}

// ---------------------------------------------------------------------------
// GEMM body (r13-verified optimum; r14's CM-chunks + split-K=4 both regressed
// and are reverted). C = A(bf16,[M,K]) * B^T(bf16,[N,K]). 64x96 tiles,
// 40 KB LDS -> 4 blocks/CU, 2-phase prefetch, one vmcnt(0)+s_barrier per
// k-tile, XOR-swizzle via pre-swizzled global source, row-major XCD remap.
// MODE 1: +bias(bq/bk/bv select), scatter q(*0.125)/k, v transposed
// MODE 2: +bias, exact GELU, bf16 row-major                    [FFN1]
// MODE 3: fp32 partial store per split (no bias)               [FFN2 split-K]
// ---------------------------------------------------------------------------
template<int MODE, int NSPLIT>
DEV void gemm_body(
    const short* __restrict__ A, const short* __restrict__ Bt,
    const float* __restrict__ bias, const float* __restrict__ biask,
    const float* __restrict__ biasv,
    float* __restrict__ outf, short* __restrict__ o0,
    short* __restrict__ o1, short* __restrict__ o2,
    int M, int N, int K)
{
    constexpr int BM = 64, BN = 96, BK = 64;
    constexpr int FM = 2, FN = 3;
    __shared__ __align__(16) short As[2][BM * BK];   // 16 KB
    __shared__ __align__(16) short Bs[2][BN * BK];   // 24 KB

    const int tid  = threadIdx.x;
    const int w    = tid >> 6, lane = tid & 63;
    const int wr   = w >> 1,  wc   = w & 1;
    const int l16  = lane & 15, lhi = lane >> 4, sw = lane & 7;

    // bijective XCD-aware remap of the (x,y) grid (all grids have nwg%8==0)
    const int gx   = gridDim.x;
    const int nwg  = gx * gridDim.y;
    const int flat = blockIdx.y * gx + blockIdx.x;
    const int nf   = (flat & 7) * (nwg >> 3) + (flat >> 3);
    const int bx   = nf % gx, by = nf / gx;

    const int kz = (NSPLIT > 1) ? blockIdx.z : 0;

    const short* Ab = A  + (long)by * BM * K;
    const short* Bb = Bt + (long)bx * BN * K;

    const int ktPer = (K >> 6) / NSPLIT;
    const int ktBeg = kz * ktPer, ktEnd = ktBeg + ktPer;

    f32x4 acc[FM][FN];
#pragma unroll
    for (int m = 0; m < FM; ++m)
#pragma unroll
        for (int n = 0; n < FN; ++n) acc[m][n] = (f32x4)(0.0f);

    auto stage = [&](int buf, int kt) {
        const short* Ag = Ab + kt * BK;
#pragma unroll
        for (int i = 0; i < BM / 32; ++i) {          // 2 calls: 512 segs
            int seg = i * 256 + tid;
            int row = seg >> 3;                      // 0..63
            int gcs = (seg & 7) ^ (row & 7);         // pre-swizzled source
            gload_lds16(Ag + (long)row * K + gcs * 8, &As[buf][(i * 256 + w * 64) * 8]);
        }
        const short* Bg = Bb + kt * BK;
#pragma unroll
        for (int i = 0; i < BN / 32; ++i) {          // 3 calls: 768 segs
            int seg = i * 256 + tid;
            int row = seg >> 3;                      // 0..95
            int gcs = (seg & 7) ^ (row & 7);
            gload_lds16(Bg + (long)row * K + gcs * 8, &Bs[buf][(i * 256 + w * 64) * 8]);
        }
    };

    stage(0, ktBeg);
    asm volatile("s_waitcnt vmcnt(0)" ::: "memory");
    __builtin_amdgcn_s_barrier();

    int cur = 0;
    for (int kt = ktBeg; kt < ktEnd; ++kt) {
        if (kt + 1 < ktEnd) stage(cur ^ 1, kt + 1);     // prefetch next tile
        const short* Ac = &As[cur][0];
        const short* Bc = &Bs[cur][0];
#pragma unroll
        for (int kk = 0; kk < 2; ++kk) {
            bf16x8 af[FM], bfr[FN];
#pragma unroll
            for (int m = 0; m < FM; ++m) {
                int ar = wr * 32 + m * 16 + l16;
                int ks = (kk * 4 + lhi) ^ sw;           // ar&7 == sw
                af[m] = *(const bf16x8*)(Ac + ar * BK + ks * 8);
            }
#pragma unroll
            for (int n = 0; n < FN; ++n) {
                int br = wc * 48 + n * 16 + l16;
                int ks = (kk * 4 + lhi) ^ sw;           // br&7 == sw
                bfr[n] = *(const bf16x8*)(Bc + br * BK + ks * 8);
            }
#pragma unroll
            for (int m = 0; m < FM; ++m)
#pragma unroll
                for (int n = 0; n < FN; ++n)
                    acc[m][n] = __builtin_amdgcn_mfma_f32_16x16x32_bf16(
                        af[m], bfr[n], acc[m][n], 0, 0, 0);
        }
        asm volatile("s_waitcnt vmcnt(0)" ::: "memory");
        __builtin_amdgcn_s_barrier();
        cur ^= 1;
    }

    // Epilogue. C/D frag mapping: col = lane&15, row = (lane>>4)*4 + reg.
    const int m0 = by * BM, n0 = bx * BN;
#pragma unroll
    for (int m = 0; m < FM; ++m) {
#pragma unroll
        for (int n = 0; n < FN; ++n) {
            const int grow0 = m0 + wr * 32 + m * 16 + lhi * 4;
            const int gcol  = n0 + wc * 48 + n * 16 + l16;
#pragma unroll
            for (int r = 0; r < 4; ++r) {
                float val = acc[m][n][r];
                int grow = grow0 + r;
                if constexpr (MODE == 1) {
                    int d  = gcol & 63;
                    int hh = gcol >> 6;                 // 0..35
                    float bval = (hh < 12) ? bias[gcol]
                               : (hh < 24) ? biask[gcol - 768]
                                           : biasv[gcol - 1536];
                    float v = val + bval;
                    int bb = grow >> 9, s = grow & 511;
                    if (hh < 12) {
                        o0[((long)((bb * 12 + hh) * 512 + s) << 6) + d] = f2b(v * 0.125f);
                    } else if (hh < 24) {
                        o1[((long)((bb * 12 + (hh - 12)) * 512 + s) << 6) + d] = f2b(v);
                    } else {                             // V stored transposed [B,H,64,512]
                        o2[((long)((bb * 12 + (hh - 24)) * 64 + d) << 9) + s] = f2b(v);
                    }
                } else if constexpr (MODE == 2) {
                    float v = val + bias[gcol];
                    v = 0.5f * v * (1.0f + erff(v * 0.70710678118f));
                    o0[(long)grow * N + gcol] = f2b(v);
                } else {                                 // MODE 3: fp32 partial store
                    outf[(long)kz * M * N + (long)grow * N + gcol] = val;
                }
            }
        }
    }
}

__global__ __launch_bounds__(256) void k_qkv(
    const short* A, const short* Bt,
    const float* bq, const float* bk, const float* bv,
    short* q, short* k, short* vt)
{ gemm_body<1, 1>(A, Bt, bq, bk, bv, nullptr, q, k, vt, 2048, 2304, 768); }

__global__ __launch_bounds__(256) void k_ffn1(
    const short* A, const short* Bt, const float* bias, short* h)
{ gemm_body<2, 1>(A, Bt, bias, nullptr, nullptr, nullptr, h, nullptr, nullptr, 2048, 3072, 768); }

__global__ __launch_bounds__(256) void k_ffn2(
    const short* A, const short* Bt, float* part)
{ gemm_body<3, 2>(A, Bt, nullptr, nullptr, nullptr, part, nullptr, nullptr, nullptr, 2048, 768, 3072); }

// ---------------------------------------------------------------------------
// Fused flash attention (r13-verified). One block per (64-row q-tile, head).
// Swapped QK^T; fixed-shift softmax p = exp(s - 8) (scores bounded << 88);
// packed short4 P-writes; K/V KVBLK=64 dbuf 2-phase.
// x += O (rows/cols exclusive -> plain +=).
// ---------------------------------------------------------------------------
__global__ __launch_bounds__(256) void k_attn(
    const short* __restrict__ Qg,   // [48][512][64] bf16, pre-scaled by 1/8
    const short* __restrict__ Kg,   // [48][512][64]
    const short* __restrict__ VTg,  // [48][64][512]  (V^T per head)
    float* __restrict__ x)          // [2048][768] +=
{
    __shared__ __align__(16) short Qs[64 * 64];        // 8 KB
    __shared__ __align__(16) short Ks[2][64 * 64];     // 16 KB
    __shared__ __align__(16) short Vs[2][64 * 64];     // 16 KB
    __shared__ __align__(16) short Ps[4][16 * 64];     // 8 KB (per-wave P tile)

    const int tid = threadIdx.x;
    const int w = tid >> 6, lane = tid & 63;
    const int l16 = lane & 15, lhi = lane >> 4;

    // XCD grouping: 48 consecutive nf (6 heads) per XCD
    const int f  = blockIdx.y * 8 + blockIdx.x;        // z*8 + qt
    const int nf = (f & 7) * 48 + (f >> 3);
    const int z  = nf >> 3, qt = nf & 7;
    const int q0 = qt * 64;

    const short* Qb = Qg  + (long)z * 512 * 64 + q0 * 64;   // contiguous 64x64
    const short* Kb = Kg  + (long)z * 512 * 64;
    const short* Vb = VTg + (long)z * 64 * 512;

    auto stageQ = [&]() {
#pragma unroll
        for (int i = 0; i < 2; ++i) {
            int seg = i * 256 + tid;
            int row = seg >> 3;
            int gc  = (seg & 7) ^ (row & 7);
            gload_lds16(Qb + row * 64 + gc * 8, Qs + (i * 256 + w * 64) * 8);
        }
    };
    auto stageK = [&](int buf, int kt) {
#pragma unroll
        for (int i = 0; i < 2; ++i) {
            int seg = i * 256 + tid;
            int row = seg >> 3;
            int gc  = (seg & 7) ^ (row & 7);
            gload_lds16(Kb + (kt * 64 + row) * 64 + gc * 8, &Ks[buf][(i * 256 + w * 64) * 8]);
        }
    };
    auto stageV = [&](int buf, int kt) {
#pragma unroll
        for (int i = 0; i < 2; ++i) {
            int seg = i * 256 + tid;
            int row = seg >> 3;                         // d index
            int gc  = (seg & 7) ^ (row & 7);
            gload_lds16(Vb + (long)row * 512 + kt * 64 + gc * 8, &Vs[buf][(i * 256 + w * 64) * 8]);
        }
    };

    stageQ(); stageK(0, 0); stageV(0, 0);
    asm volatile("s_waitcnt vmcnt(0)" ::: "memory");
    __syncthreads();

    // Q b-frags for wave's 16 q-rows (row = w*16 + l16), loaded once
    bf16x8 bq[2];
    {
        int qr = w * 16 + l16;
#pragma unroll
        for (int kk = 0; kk < 2; ++kk)
            bq[kk] = *(const bf16x8*)(Qs + qr * 64 + (((kk * 4 + lhi) ^ (l16 & 7)) * 8));
    }

    float l = 0.0f;
    f32x4 acc[4];
#pragma unroll
    for (int bn = 0; bn < 4; ++bn) acc[bn] = (f32x4)(0.0f);

    int cur = 0;
    for (int kt = 0; kt < 8; ++kt) {
        if (kt < 7) { stageK(cur ^ 1, kt + 1); stageV(cur ^ 1, kt + 1); }

        // S^T = K_tile(64 kpos x 64 d) · Q^T : lane holds S[q=l16][k=km*16+lhi*4+r]
        f32x4 s[4];
#pragma unroll
        for (int km = 0; km < 4; ++km) s[km] = (f32x4)(0.0f);
#pragma unroll
        for (int kk = 0; kk < 2; ++kk) {
#pragma unroll
            for (int km = 0; km < 4; ++km) {
                int kr = km * 16 + l16;
                bf16x8 ak = *(const bf16x8*)(&Ks[cur][kr * 64 + (((kk * 4 + lhi) ^ (l16 & 7)) * 8)]);
                s[km] = __builtin_amdgcn_mfma_f32_16x16x32_bf16(ak, bq[kk], s[km], 0, 0, 0);
            }
        }

        // fixed-shift softmax accumulation for q = l16 (no max tracking)
        float p[16];
        float ts = 0.0f;
#pragma unroll
        for (int km = 0; km < 4; ++km)
#pragma unroll
            for (int r = 0; r < 4; ++r) {
                float e = __expf(s[km][r] - 8.0f);
                p[km * 4 + r] = e; ts += e;
            }
        ts += __shfl_xor(ts, 16);
        ts += __shfl_xor(ts, 32);
        l += ts;

        // packed P write (bf16) to per-wave LDS tile in A-frag layout.
        // k = km*16 + lhi*4 + r -> granule g = 2km + (lhi>>1), elem e = (lhi&1)*4 + r
        {
            short* Pw = &Ps[w][0];
#pragma unroll
            for (int km = 0; km < 4; ++km) {
                int g = km * 2 + (lhi >> 1);
                short4 pk;
                pk.x = f2b(p[km * 4 + 0]);
                pk.y = f2b(p[km * 4 + 1]);
                pk.z = f2b(p[km * 4 + 2]);
                pk.w = f2b(p[km * 4 + 3]);
                *(short4*)(Pw + l16 * 64 + ((g ^ (l16 & 7)) * 8) + (lhi & 1) * 4) = pk;
            }
        }

        // PV: O(16q x 64d) += P(16q x 64k) · V(64k x 64d)
#pragma unroll
        for (int kk = 0; kk < 2; ++kk) {
            bf16x8 ap = *(const bf16x8*)(&Ps[w][l16 * 64 + (((kk * 4 + lhi) ^ (l16 & 7)) * 8)]);
#pragma unroll
            for (int bn = 0; bn < 4; ++bn) {
                int vr = bn * 16 + l16;
                bf16x8 bv = *(const bf16x8*)(&Vs[cur][vr * 64 + (((kk * 4 + lhi) ^ (l16 & 7)) * 8)]);
                acc[bn] = __builtin_amdgcn_mfma_f32_16x16x32_bf16(ap, bv, acc[bn], 0, 0, 0);
            }
        }

        asm volatile("s_waitcnt vmcnt(0)" ::: "memory");
        __builtin_amdgcn_s_barrier();
        cur ^= 1;
    }

    // epilogue: normalize and accumulate into x
    float inv = 1.0f / l;
    float invr[4];
#pragma unroll
    for (int r = 0; r < 4; ++r) invr[r] = __shfl(inv, lhi * 4 + r);
    const int zb = z / 12, zh = z - (z / 12) * 12;
#pragma unroll
    for (int bn = 0; bn < 4; ++bn)
#pragma unroll
        for (int r = 0; r < 4; ++r) {
            long idx = ((long)(zb * 512 + q0 + w * 16 + lhi * 4 + r)) * 768 + zh * 64 + bn * 16 + l16;
            x[idx] += acc[bn][r] * invr[r];
        }
}

// ---------------------------------------------------------------------------
// LayerNorm: one wave per row (768 fp32), write bf16
// ---------------------------------------------------------------------------
__global__ __launch_bounds__(256) void k_ln(
    const float* __restrict__ x, const float* __restrict__ g,
    const float* __restrict__ be, short* __restrict__ out)
{
    int row  = blockIdx.x * 4 + (threadIdx.x >> 6);
    int lane = threadIdx.x & 63;
    const float4* xr = (const float4*)(x + (long)row * 768);
    float4 v0 = xr[lane], v1 = xr[lane + 64], v2 = xr[lane + 128];
    float f[12] = {v0.x, v0.y, v0.z, v0.w, v1.x, v1.y, v1.z, v1.w, v2.x, v2.y, v2.z, v2.w};

    float s = 0.f;
#pragma unroll
    for (int j = 0; j < 12; ++j) s += f[j];
#pragma unroll
    for (int o = 32; o; o >>= 1) s += __shfl_xor(s, o);
    float mu = s * (1.0f / 768.0f);
    float s2 = 0.f;
#pragma unroll
    for (int j = 0; j < 12; ++j) { f[j] -= mu; s2 += f[j] * f[j]; }
#pragma unroll
    for (int o = 32; o; o >>= 1) s2 += __shfl_xor(s2, o);
    float rstd = rsqrtf(s2 * (1.0f / 768.0f) + 1e-5f);

    const float4* gr = (const float4*)g;
    const float4* br = (const float4*)be;
    short4* orow = (short4*)(out + (long)row * 768);
#pragma unroll
    for (int jb = 0; jb < 3; ++jb) {
        float4 gg = gr[lane + 64 * jb], bb = br[lane + 64 * jb];
        short4 o4;
        o4.x = f2b(f[4 * jb + 0] * rstd * gg.x + bb.x);
        o4.y = f2b(f[4 * jb + 1] * rstd * gg.y + bb.y);
        o4.z = f2b(f[4 * jb + 2] * rstd * gg.z + bb.z);
        o4.w = f2b(f[4 * jb + 3] * rstd * gg.w + bb.w);
        orow[lane + 64 * jb] = o4;
    }
}

// ---------------------------------------------------------------------------
// FFN2 split-K reduce fused with next block's LN1:
//   x += p0 + p1 + b1 ; if DO_LN: lnb = LN(x)*g + be  (one wave per row)
// ---------------------------------------------------------------------------
template<int DO_LN>
__global__ __launch_bounds__(256) void k_redln(
    const float* __restrict__ part, const float* __restrict__ bias,
    float* __restrict__ x, const float* __restrict__ g,
    const float* __restrict__ be, short* __restrict__ out)
{
    int row  = blockIdx.x * 4 + (threadIdx.x >> 6);
    int lane = threadIdx.x & 63;
    const float4* p0 = (const float4*)part + (long)row * 192;
    const float4* p1 = (const float4*)(part + 2048l * 768) + (long)row * 192;
    const float4* b4 = (const float4*)bias;
    float4* xr = (float4*)(x + (long)row * 768);

    float f[12];
#pragma unroll
    for (int jb = 0; jb < 3; ++jb) {
        int idx = lane + 64 * jb;
        float4 a = p0[idx], b = p1[idx], c = b4[idx], xv = xr[idx];
        xv.x += a.x + b.x + c.x;
        xv.y += a.y + b.y + c.y;
        xv.z += a.z + b.z + c.z;
        xv.w += a.w + b.w + c.w;
        xr[idx] = xv;
        f[4 * jb + 0] = xv.x; f[4 * jb + 1] = xv.y;
        f[4 * jb + 2] = xv.z; f[4 * jb + 3] = xv.w;
    }

    if constexpr (DO_LN) {
        float s = 0.f;
#pragma unroll
        for (int j = 0; j < 12; ++j) s += f[j];
#pragma unroll
        for (int o = 32; o; o >>= 1) s += __shfl_xor(s, o);
        float mu = s * (1.0f / 768.0f);
        float s2 = 0.f;
#pragma unroll
        for (int j = 0; j < 12; ++j) { f[j] -= mu; s2 += f[j] * f[j]; }
#pragma unroll
        for (int o = 32; o; o >>= 1) s2 += __shfl_xor(s2, o);
        float rstd = rsqrtf(s2 * (1.0f / 768.0f) + 1e-5f);

        const float4* gr = (const float4*)g;
        const float4* br = (const float4*)be;
        short4* orow = (short4*)(out + (long)row * 768);
#pragma unroll
        for (int jb = 0; jb < 3; ++jb) {
            float4 gg = gr[lane + 64 * jb], bb = br[lane + 64 * jb];
            short4 o4;
            o4.x = f2b(f[4 * jb + 0] * rstd * gg.x + bb.x);
            o4.y = f2b(f[4 * jb + 1] * rstd * gg.y + bb.y);
            o4.z = f2b(f[4 * jb + 2] * rstd * gg.z + bb.z);
            o4.w = f2b(f[4 * jb + 3] * rstd * gg.w + bb.w);
            orow[lane + 64 * jb] = o4;
        }
    }
}

// ---------------------------------------------------------------------------
// Weight prep kernels
// ---------------------------------------------------------------------------
__global__ __launch_bounds__(256) void transpose_w(
    const float* __restrict__ in, short* __restrict__ out, int R, int C)
{
    __shared__ float t[32][33];
    int r0 = blockIdx.y * 32, c0 = blockIdx.x * 32;
    int tx = threadIdx.x & 31, ty = threadIdx.x >> 5;
#pragma unroll
    for (int p = 0; p < 4; ++p)
        t[ty + 8 * p][tx] = in[(long)(r0 + ty + 8 * p) * C + c0 + tx];
    __syncthreads();
#pragma unroll
    for (int p = 0; p < 4; ++p)
        out[(long)(c0 + ty + 8 * p) * R + r0 + tx] = f2b(t[tx][ty + 8 * p]);
}

// merged 3-way 768x768 transpose (Wq/Wk/Wv)
__global__ __launch_bounds__(256) void transpose_w3(
    const float* __restrict__ Wq, const float* __restrict__ Wk,
    const float* __restrict__ Wv, short* __restrict__ out)
{
    const float* in = (blockIdx.z == 0) ? Wq : (blockIdx.z == 1) ? Wk : Wv;
    short* o = out + (long)blockIdx.z * 768 * 768;
    __shared__ float t[32][33];
    int r0 = blockIdx.y * 32, c0 = blockIdx.x * 32;
    int tx = threadIdx.x & 31, ty = threadIdx.x >> 5;
#pragma unroll
    for (int p = 0; p < 4; ++p)
        t[ty + 8 * p][tx] = in[(long)(r0 + ty + 8 * p) * 768 + c0 + tx];
    __syncthreads();
#pragma unroll
    for (int p = 0; p < 4; ++p)
        o[(long)(c0 + ty + 8 * p) * 768 + r0 + tx] = f2b(t[tx][ty + 8 * p]);
}

// ---------------------------------------------------------------------------
// Host launcher
// ---------------------------------------------------------------------------
extern "C" void kernel_launch(void* const* d_in, const int* in_sizes, int n_in,
                              void* d_out, int out_size, void* d_ws, size_t ws_size,
                              hipStream_t stream)
{
    (void)in_sizes; (void)n_in; (void)out_size; (void)ws_size;
    const float* x_in = (const float*)d_in[0];
    const float* Wq  = (const float*)d_in[1];
    const float* bq  = (const float*)d_in[2];
    const float* Wk  = (const float*)d_in[3];
    const float* bk  = (const float*)d_in[4];
    const float* Wv  = (const float*)d_in[5];
    const float* bv  = (const float*)d_in[6];
    const float* g1  = (const float*)d_in[7];
    const float* be1 = (const float*)d_in[8];
    const float* g2  = (const float*)d_in[9];
    const float* be2 = (const float*)d_in[10];
    const float* W0  = (const float*)d_in[11];
    const float* b0  = (const float*)d_in[12];
    const float* W1  = (const float*)d_in[13];
    const float* b1  = (const float*)d_in[14];

    float* x = (float*)d_out;   // residual stream lives in d_out, fp32 [2048,768]

    char* ws = (char*)d_ws;
    size_t off = 0;
    auto alloc = [&](size_t bytes) -> char* {
        char* p = ws + off; off = (off + bytes + 255) & ~(size_t)255; return p;
    };
    short* wqkvt = (short*)alloc(2304l * 768 * 2);   // [Wq^T;Wk^T;Wv^T]
    short* w0t   = (short*)alloc(3072l * 768 * 2);
    short* w1t   = (short*)alloc(768l * 3072 * 2);
    short* lnb   = (short*)alloc(2048l * 768 * 2);   // LN output
    short* q     = (short*)alloc(2048l * 768 * 2);   // [B,H,512,64], pre-scaled 1/8
    short* k     = (short*)alloc(2048l * 768 * 2);   // [B,H,512,64]
    short* vt    = (short*)alloc(2048l * 768 * 2);   // [B,H,64,512]  (V^T)
    short* h     = (short*)alloc(2048l * 3072 * 2);  // FFN hidden
    float* part  = (float*)alloc(2l * 2048 * 768 * 4); // FFN2 split-K partials

    hipMemcpyAsync(x, x_in, 2048l * 768 * 4, hipMemcpyDeviceToDevice, stream);

    transpose_w3<<<dim3(24, 24, 3), 256, 0, stream>>>(Wq, Wk, Wv, wqkvt);
    transpose_w<<<dim3(96, 24), 256, 0, stream>>>(W0, w0t, 768, 3072);
    transpose_w<<<dim3(24, 96), 256, 0, stream>>>(W1, w1t, 3072, 768);

    for (int it = 0; it < 12; ++it) {
        if (it == 0)
            k_ln<<<512, 256, 0, stream>>>(x, g1, be1, lnb);
        // QKV: 64x96 tiles, 768 blocks, V written transposed
        k_qkv<<<dim3(24, 32), 256, 0, stream>>>(lnb, wqkvt, bq, bk, bv, q, k, vt);
        // fused flash attention: x += softmax(q k^T) v
        k_attn<<<dim3(8, 48), 256, 0, stream>>>(q, k, vt, x);
        // LN2
        k_ln<<<512, 256, 0, stream>>>(x, g2, be2, lnb);
        // h = gelu(ln2 @ W0 + b0): 64x96 tiles, 1024 blocks
        k_ffn1<<<dim3(32, 32), 256, 0, stream>>>(lnb, w0t, b0, h);
        // FFN2: 64x96 tiles, split-K=2 fp32 partials, 512 blocks
        k_ffn2<<<dim3(8, 32, 2), 256, 0, stream>>>(h, w1t, part);
        // x += p0 + p1 + b1, fused with LN1 of the next block
        if (it < 11)
            k_redln<1><<<512, 256, 0, stream>>>(part, b1, x, g1, be1, lnb);
        else
            k_redln<0><<<512, 256, 0, stream>>>(part, b1, x, nullptr, nullptr, nullptr);
    }
}